// Round 4
// baseline (494.097 us; speedup 1.0000x reference)
//
#include <hip/hip_runtime.h>
#include <math.h>

#define Bn 32
#define Sn 512
#define Hn 1024
#define Tn 8
#define Nn 16
#define Gn 4096

#define ACC4(A,W,V) A.x = fmaf(W, V.x, A.x); A.y = fmaf(W, V.y, A.y); A.z = fmaf(W, V.z, A.z); A.w = fmaf(W, V.w, A.w)

__device__ __forceinline__ float wsum(float v){
#pragma unroll
  for (int off = 32; off; off >>= 1) v += __shfl_xor(v, off);
  return v;
}

__device__ __forceinline__ float dot16(float4 a0, float4 a1, float4 a2, float4 a3,
                                       float4 v0, float4 v1, float4 v2, float4 v3){
  float d = a0.x*v0.x + a0.y*v0.y + a0.z*v0.z + a0.w*v0.w;
  d += a1.x*v1.x + a1.y*v1.y + a1.z*v1.z + a1.w*v1.w;
  d += a2.x*v2.x + a2.y*v2.y + a2.z*v2.z + a2.w*v2.w;
  d += a3.x*v3.x + a3.y*v3.y + a3.z*v3.z + a3.w*v3.w;
  return d;
}

// ---------------- utility kernels ----------------

__global__ __launch_bounds__(256) void transpose1024(const float* __restrict__ in, float* __restrict__ out){
  __shared__ float tile[32][33];
  int tx = threadIdx.x & 31, ty = threadIdx.x >> 5;
  int c0 = blockIdx.x * 32, r0 = blockIdx.y * 32;
#pragma unroll
  for (int k = 0; k < 4; ++k)
    tile[ty + 8*k][tx] = in[(size_t)(r0 + ty + 8*k) * Hn + c0 + tx];
  __syncthreads();
#pragma unroll
  for (int k = 0; k < 4; ++k)
    out[(size_t)(c0 + ty + 8*k) * Hn + r0 + tx] = tile[tx][ty + 8*k];
}

__global__ __launch_bounds__(256) void copy_nums(const float4* __restrict__ nums, float4* __restrict__ un){
  int n = blockIdx.x, b = blockIdx.y;
  un[((size_t)b*(Nn+Tn) + n)*256 + threadIdx.x] = nums[((size_t)b*Nn + n)*256 + threadIdx.x];
}

__global__ __launch_bounds__(256) void init_xs(const float4* __restrict__ pq, float4* __restrict__ xs){
  int b = blockIdx.x;
  xs[((size_t)b*Tn)*256 + threadIdx.x] = pq[(size_t)b*256 + threadIdx.x];
}

__global__ __launch_bounds__(256) void finalize_xs(const float4* __restrict__ xs, float4* __restrict__ uh, float4* __restrict__ un){
  int t = blockIdx.x, b = blockIdx.y;
  float4 v = xs[((size_t)b*Tn + t)*256 + threadIdx.x];
  uh[(((size_t)(Sn + t))*Bn + b)*256 + threadIdx.x] = v;
  un[((size_t)b*(Nn+Tn) + Nn + t)*256 + threadIdx.x] = v;
}

// ---------------- attention (gen loop), all-f32 ----------------
// grid (16, B), block 512 = 8 waves x 4 rows. Phase 1: 4 independent dot
// chains + 4 independent butterflies per wave. Block max via LDS. Phase 2:
// weighted accumulate (rows re-read; block-local so L2-hot). Block combine
// -> 16 partials per b. FIRST also emits uh (folds the 64MB hidden copy).
template<int FIRST>
__global__ __launch_bounds__(512) void attend3(
    const float* __restrict__ hidden, const float* __restrict__ xk,
    float* __restrict__ ctxp, float* __restrict__ mlp, float* __restrict__ uh)
{
  const int b = blockIdx.y, p = blockIdx.x;
  const int lane = threadIdx.x & 63, w = threadIdx.x >> 6;
  const int s0 = p*32 + w*4;
  const float4* xq = (const float4*)(xk + (size_t)b*Hn) + lane*4;
  float4 q0 = xq[0], q1 = xq[1], q2 = xq[2], q3 = xq[3];

  size_t roff[4];
  float d[4];
#pragma unroll
  for (int r = 0; r < 4; ++r) roff[r] = ((size_t)(s0+r)*Bn + b)*Hn;
#pragma unroll
  for (int r = 0; r < 4; ++r){
    const float4* row = (const float4*)(hidden + roff[r]) + lane*4;
    float4 v0 = row[0], v1 = row[1], v2 = row[2], v3 = row[3];
    d[r] = dot16(q0,q1,q2,q3, v0,v1,v2,v3);
  }
#pragma unroll
  for (int r = 0; r < 4; ++r){
#pragma unroll
    for (int off = 32; off; off >>= 1) d[r] += __shfl_xor(d[r], off);
  }
  float mw = fmaxf(fmaxf(d[0], d[1]), fmaxf(d[2], d[3]));

  __shared__ float sM[8], sL[8];
  __shared__ float sacc[8*1024];
  sM[w] = mw;
  __syncthreads();
  float M = sM[0];
#pragma unroll
  for (int i = 1; i < 8; ++i) M = fmaxf(M, sM[i]);
  float wr[4], lw = 0.f;
#pragma unroll
  for (int r = 0; r < 4; ++r){ wr[r] = __expf(d[r] - M); lw += wr[r]; }

  float4 a0 = make_float4(0,0,0,0), a1 = a0, a2 = a0, a3 = a0;
#pragma unroll
  for (int r = 0; r < 4; ++r){
    const float4* row = (const float4*)(hidden + roff[r]) + lane*4;
    float4 v0 = row[0], v1 = row[1], v2 = row[2], v3 = row[3];
    if (FIRST){
      float4* ur = (float4*)(uh + roff[r]) + lane*4;
      ur[0] = v0; ur[1] = v1; ur[2] = v2; ur[3] = v3;
    }
    ACC4(a0, wr[r], v0); ACC4(a1, wr[r], v1); ACC4(a2, wr[r], v2); ACC4(a3, wr[r], v3);
  }
  float4* sa = (float4*)(sacc + w*1024) + lane*4;
  sa[0] = a0; sa[1] = a1; sa[2] = a2; sa[3] = a3;
  sL[w] = lw;
  __syncthreads();
  const int tid = threadIdx.x;
#pragma unroll
  for (int c0 = 0; c0 < 1024; c0 += 512){
    int c = c0 + tid;
    float s = sacc[c];
#pragma unroll
    for (int i = 1; i < 8; ++i) s += sacc[i*1024 + c];
    ctxp[((size_t)b*16 + p)*1024 + c] = s;
  }
  if (tid == 0){
    float L = 0.f;
#pragma unroll
    for (int i = 0; i < 8; ++i) L += sL[i];
    mlp[((size_t)b*16 + p)*2]     = M;
    mlp[((size_t)b*16 + p)*2 + 1] = L;
  }
}

// merge 16 partials per b. grid (4, B), block 64.
__global__ __launch_bounds__(64) void combine3(
    const float* __restrict__ ctxp, const float* __restrict__ mlp, float* __restrict__ ctx)
{
  int b = blockIdx.y, hc = blockIdx.x, lane = threadIdx.x;
  float m[16], l[16];
  float M = -1e30f;
#pragma unroll
  for (int i = 0; i < 16; ++i){
    m[i] = mlp[((size_t)b*16 + i)*2];
    l[i] = mlp[((size_t)b*16 + i)*2 + 1];
    M = fmaxf(M, m[i]);
  }
  float L = 0.f, wgt[16];
#pragma unroll
  for (int i = 0; i < 16; ++i){ wgt[i] = __expf(m[i] - M); L = fmaf(l[i], wgt[i], L); }
  float4 acc = make_float4(0,0,0,0);
  const float* cp = ctxp + (size_t)b*16*1024 + hc*256 + lane*4;
#pragma unroll 4
  for (int i = 0; i < 16; ++i){
    float4 v = *(const float4*)(cp + (size_t)i*1024);
    ACC4(acc, wgt[i], v);
  }
  float inv = 1.f / L;
  acc.x *= inv; acc.y *= inv; acc.z *= inv; acc.w *= inv;
  *(float4*)(ctx + (size_t)b*Hn + hc*256 + lane*4) = acc;
}

// ---------------- split-K register-tiled matvec ----------------
__global__ __launch_bounds__(256) void mv1(
    const float* __restrict__ X, int xstride,
    const float* __restrict__ M, float* __restrict__ part,
    int nj, int ktiles)
{
  __shared__ float wt[64*128];
  __shared__ float xl[64*32];
  const int t  = threadIdx.x;
  const int j0 = blockIdx.x * 128;
  const int kb = blockIdx.y;
  const int r0 = blockIdx.z * 32;
  const int R  = gridDim.z * 32;
  const int tj = t & 31, tr = t >> 5;
  float acc[4][4] = {{0.f,0.f,0.f,0.f},{0.f,0.f,0.f,0.f},{0.f,0.f,0.f,0.f},{0.f,0.f,0.f,0.f}};

  for (int kt = 0; kt < ktiles; ++kt){
    const int k0 = (kb*ktiles + kt)*64;
    __syncthreads();
    {
      int j = t >> 1;
      int kqb = (t & 1) * 8;
      const float* Mrow = M + (size_t)(j0 + j)*1024 + k0;
#pragma unroll
      for (int c = 0; c < 8; ++c){
        float4 v = *(const float4*)(Mrow + (kqb + c)*4);
        int kk = (kqb + c)*4;
        wt[(kk+0)*128 + j] = v.x;
        wt[(kk+1)*128 + j] = v.y;
        wt[(kk+2)*128 + j] = v.z;
        wt[(kk+3)*128 + j] = v.w;
      }
      int r = t >> 3;
      int kq0 = t & 7;
#pragma unroll
      for (int c = 0; c < 2; ++c){
        int kk = (kq0 + c*8)*4;
        float4 v = *(const float4*)(X + (size_t)(r0 + r)*xstride + k0 + kk);
        xl[(kk+0)*32 + r] = v.x;
        xl[(kk+1)*32 + r] = v.y;
        xl[(kk+2)*32 + r] = v.z;
        xl[(kk+3)*32 + r] = v.w;
      }
    }
    __syncthreads();
#pragma unroll 4
    for (int k = 0; k < 64; ++k){
      float4 w4 = *(const float4*)(wt + k*128 + tj*4);
      float4 x4 = *(const float4*)(xl + k*32  + tr*4);
      acc[0][0] = fmaf(x4.x, w4.x, acc[0][0]);
      acc[0][1] = fmaf(x4.x, w4.y, acc[0][1]);
      acc[0][2] = fmaf(x4.x, w4.z, acc[0][2]);
      acc[0][3] = fmaf(x4.x, w4.w, acc[0][3]);
      acc[1][0] = fmaf(x4.y, w4.x, acc[1][0]);
      acc[1][1] = fmaf(x4.y, w4.y, acc[1][1]);
      acc[1][2] = fmaf(x4.y, w4.z, acc[1][2]);
      acc[1][3] = fmaf(x4.y, w4.w, acc[1][3]);
      acc[2][0] = fmaf(x4.z, w4.x, acc[2][0]);
      acc[2][1] = fmaf(x4.z, w4.y, acc[2][1]);
      acc[2][2] = fmaf(x4.z, w4.z, acc[2][2]);
      acc[2][3] = fmaf(x4.z, w4.w, acc[2][3]);
      acc[3][0] = fmaf(x4.w, w4.x, acc[3][0]);
      acc[3][1] = fmaf(x4.w, w4.y, acc[3][1]);
      acc[3][2] = fmaf(x4.w, w4.z, acc[3][2]);
      acc[3][3] = fmaf(x4.w, w4.w, acc[3][3]);
    }
  }
  const size_t base = ((size_t)kb*R + r0 + tr*4)*nj + j0 + tj*4;
#pragma unroll
  for (int i = 0; i < 4; ++i)
    *(float4*)(part + base + (size_t)i*nj) = make_float4(acc[i][0], acc[i][1], acc[i][2], acc[i][3]);
}

__global__ __launch_bounds__(256) void mv2(
    const float* __restrict__ part, int R, int njshift, int KB,
    const float* __restrict__ b1, const float* __restrict__ b2,
    float* __restrict__ out, int rpgshift, int opg)
{
  int idx = blockIdx.x*256 + threadIdx.x;
  int nj = 1 << njshift;
  int r = idx >> njshift, j = idx & (nj - 1);
  float s = 0.f;
  if (b1) s += b1[j];
  if (b2) s += b2[j];
  size_t stride = (size_t)R << njshift;
  for (int kb = 0; kb < KB; ++kb) s += part[(size_t)kb*stride + idx];
  int orow = ((r >> rpgshift) * opg) + (r & ((1 << rpgshift) - 1));
  out[((size_t)orow << njshift) + j] = s;
}

// ---------------- stage-2 kernels ----------------

// grid (32, B), block 512: wave w covers t-pair (w&3), row-octet rh=w>>2.
__global__ __launch_bounds__(512) void scores2_kernel(
    const float* __restrict__ hidden, const float* __restrict__ xk2, float* __restrict__ sc)
{
  int b = blockIdx.y, p = blockIdx.x;
  int lane = threadIdx.x & 63, w = threadIdx.x >> 6;
  int t0 = (w & 3) * 2, rh = w >> 2;
  const float4* qa = (const float4*)(xk2 + ((size_t)b*Tn + t0  )*Hn) + lane*4;
  const float4* qb = (const float4*)(xk2 + ((size_t)b*Tn + t0+1)*Hn) + lane*4;
  float4 a0=qa[0], a1=qa[1], a2=qa[2], a3=qa[3];
  float4 c0=qb[0], c1=qb[1], c2=qb[2], c3=qb[3];
#pragma unroll 2
  for (int r = 0; r < 8; ++r){
    int s = p*16 + rh*8 + r;
    const float4* row = (const float4*)(hidden + ((size_t)s*Bn + b)*Hn) + lane*4;
    float4 v0=row[0], v1=row[1], v2=row[2], v3=row[3];
    float d0 = wsum(dot16(a0,a1,a2,a3, v0,v1,v2,v3));
    float d1 = wsum(dot16(c0,c1,c2,c3, v0,v1,v2,v3));
    if (lane == 0){
      sc[((size_t)b*Tn + t0  )*Sn + s] = d0;
      sc[((size_t)b*Tn + t0+1)*Sn + s] = d1;
    }
  }
}

// fused softmax + ctx2, all-f32. grid (8, B), block 512.
__global__ __launch_bounds__(512) void ctx2f(
    const float* __restrict__ hidden, const float* __restrict__ scraw, float* __restrict__ ctx2)
{
  int b = blockIdx.y, hc = blockIdx.x, tid = threadIdx.x;
  __shared__ float al[Tn*Sn];
  for (int i = tid; i < Tn*Sn; i += 512) al[i] = scraw[(size_t)b*Tn*Sn + i];
  __syncthreads();
  {
    int r = tid >> 6, lane = tid & 63;
    float mx = -1e30f;
#pragma unroll
    for (int k = 0; k < 8; ++k) mx = fmaxf(mx, al[r*Sn + lane + k*64]);
#pragma unroll
    for (int off = 32; off; off >>= 1) mx = fmaxf(mx, __shfl_xor(mx, off));
    float e[8], s = 0.f;
#pragma unroll
    for (int k = 0; k < 8; ++k){ e[k] = __expf(al[r*Sn + lane + k*64] - mx); s += e[k]; }
#pragma unroll
    for (int off = 32; off; off >>= 1) s += __shfl_xor(s, off);
    float inv = 1.f / s;
#pragma unroll
    for (int k = 0; k < 8; ++k) al[r*Sn + lane + k*64] = e[k] * inv;
  }
  __syncthreads();
  int hloc = tid & 127, tg = tid >> 7;
  int h = hc*128 + hloc;
  int t0 = tg*2;
  float acc0 = 0.f, acc1 = 0.f;
#pragma unroll 4
  for (int s = 0; s < Sn; ++s){
    float v = hidden[((size_t)s*Bn + b)*Hn + h];
    acc0 = fmaf(al[t0*Sn + s],     v, acc0);
    acc1 = fmaf(al[(t0+1)*Sn + s], v, acc1);
  }
  ctx2[((size_t)b*Tn + t0  )*Hn + h] = acc0;
  ctx2[((size_t)b*Tn + t0+1)*Hn + h] = acc1;
}

// ---------------- LSTM: fused partial-reduce + pointwise ----------------
__global__ __launch_bounds__(256) void lstm_fused(
    const float* __restrict__ part, const float* __restrict__ b_ih,
    const float* __restrict__ b_hh, float* __restrict__ fq)
{
  int idx = blockIdx.x*256 + threadIdx.x;   // 32768
  int b = idx >> 10, h = idx & 1023;
  const size_t stride = (size_t)32*Gn;
  float gi = b_ih[h] + b_hh[h];
  float gg = b_ih[2048+h] + b_hh[2048+h];
  float go = b_ih[3072+h] + b_hh[3072+h];
  for (int kb = 0; kb < 16; ++kb){
    const float* pp = part + (size_t)kb*stride + (size_t)b*Gn;
    gi += pp[h]; gg += pp[2048+h]; go += pp[3072+h];
  }
  float si = 1.f/(1.f + __expf(-gi));
  float so = 1.f/(1.f + __expf(-go));
  float c  = si * tanhf(gg);
  fq[((size_t)b*(Tn+1) + Tn)*Hn + h] = so * tanhf(c);
}

// ---------------- host ----------------

extern "C" void kernel_launch(void* const* d_in, const int* in_sizes, int n_in,
                              void* d_out, int out_size, void* d_ws, size_t ws_size,
                              hipStream_t stream) {
  const float* hidden = (const float*)d_in[0];
  const float* nums   = (const float*)d_in[1];
  const float* pq     = (const float*)d_in[2];
  const float* Wk     = (const float*)d_in[3];
  const float* Wv     = (const float*)d_in[5];
  const float* bv     = (const float*)d_in[6];
  const float* Wk2    = (const float*)d_in[7];
  const float* Wv2    = (const float*)d_in[9];
  const float* bv2    = (const float*)d_in[10];
  const float* W_ih   = (const float*)d_in[11];
  const float* b_ih   = (const float*)d_in[13];
  const float* b_hh   = (const float*)d_in[14];

  float* out = (float*)d_out;
  float* fq  = out;                                   // (B, T+1, H)
  float* uh  = out + (size_t)Bn*(Tn+1)*Hn;            // (S+T, B, H)
  float* un  = uh + (size_t)(Sn+Tn)*Bn*Hn;            // (B, N+T, H)

  // ws layout (floats); high-water 4,654,080 floats = 18.6 MB (< proven 21.25 MB).
  float* ws    = (float*)d_ws;
  float* xs    = ws;                 // 262144
  float* xk    = ws + 262144;        // 32768
  float* ctxp  = ws + 294912;        // 524288 (B*16*H)
  float* mlp   = ws + 819200;        // 1024
  float* ctx   = ws + 820224;        // 32768
  float* xk2   = ws + 852992;        // 262144
  float* sc2   = ws + 1115136;       // 131072
  float* ctx2v = ws + 1246208;       // 262144
  float* WkT   = ws + 1508352;       // 1048576
  float* Wk2T  = ws + 2556928;       // 1048576
  float* part  = ws + 3605504;       // 1048576 (gen loop: 16*32*1024; stage2: 4*256*1024)
  float* partL = WkT;                // LSTM partials 16*32*4096 = 2097152, overlay
                                     // WkT+Wk2T (both dead before the LSTM mv;
                                     // rewritten every call -> replay-safe)

  transpose1024<<<dim3(32,32), 256, 0, stream>>>(Wk,  WkT);
  transpose1024<<<dim3(32,32), 256, 0, stream>>>(Wk2, Wk2T);
  copy_nums<<<dim3(Nn, Bn), 256, 0, stream>>>((const float4*)nums, (float4*)un);
  init_xs<<<Bn, 256, 0, stream>>>((const float4*)pq, (float4*)xs);

  // xk0 = Wk^T problem_q
  mv1<<<dim3(8,16,1), 256, 0, stream>>>(pq, Hn, WkT, part, Hn, 1);
  mv2<<<128, 256, 0, stream>>>(part, 32, 10, 16, nullptr, nullptr, xk, 0, 1);

  for (int t = 1; t < Tn; ++t){
    if (t == 1) attend3<1><<<dim3(16,Bn), 512, 0, stream>>>(hidden, xk, ctxp, mlp, uh);
    else        attend3<0><<<dim3(16,Bn), 512, 0, stream>>>(hidden, xk, ctxp, mlp, uh);
    combine3<<<dim3(4,Bn), 64, 0, stream>>>(ctxp, mlp, ctx);
    mv1<<<dim3(8,16,1), 256, 0, stream>>>(ctx, Hn, Wv, part, Hn, 1);
    mv2<<<128, 256, 0, stream>>>(part, 32, 10, 16, bv, nullptr, xs + (size_t)t*Hn, 0, Tn);
    if (t < Tn-1){
      mv1<<<dim3(8,16,1), 256, 0, stream>>>(xs + (size_t)t*Hn, Tn*Hn, WkT, part, Hn, 1);
      mv2<<<128, 256, 0, stream>>>(part, 32, 10, 16, nullptr, nullptr, xk, 0, 1);
    }
  }

  // stage 2
  mv1<<<dim3(8,4,8), 256, 0, stream>>>(xs, Hn, Wk2T, part, Hn, 4);
  mv2<<<1024, 256, 0, stream>>>(part, 256, 10, 4, nullptr, nullptr, xk2, 0, 1);
  scores2_kernel<<<dim3(32, Bn), 512, 0, stream>>>(hidden, xk2, sc2);
  ctx2f<<<dim3(8, Bn), 512, 0, stream>>>(hidden, sc2, ctx2v);
  mv1<<<dim3(8,4,8), 256, 0, stream>>>(ctx2v, Hn, Wv2, part, Hn, 4);
  mv2<<<1024, 256, 0, stream>>>(part, 256, 10, 4, bv2, nullptr, fq, 3, Tn+1);

  // LSTM step 1 (partials overlay WkT/Wk2T -- dead by now)
  mv1<<<dim3(32,16,1), 256, 0, stream>>>(fq, (Tn+1)*Hn, W_ih, partL, Gn, 1);
  lstm_fused<<<128, 256, 0, stream>>>(partL, b_ih, b_hh, fq);

  finalize_xs<<<dim3(Tn, Bn), 256, 0, stream>>>((const float4*)xs, (float4*)uh, (float4*)un);
}

// Round 5
// 400.977 us; speedup vs baseline: 1.2322x; 1.2322x over previous
//
#include <hip/hip_runtime.h>
#include <math.h>

#define Bn 32
#define Sn 512
#define Hn 1024
#define Tn 8
#define Nn 16
#define Gn 4096

#define ACC4(A,W,V) A.x = fmaf(W, V.x, A.x); A.y = fmaf(W, V.y, A.y); A.z = fmaf(W, V.z, A.z); A.w = fmaf(W, V.w, A.w)

__device__ __forceinline__ float wsum(float v){
#pragma unroll
  for (int off = 32; off; off >>= 1) v += __shfl_xor(v, off);
  return v;
}

__device__ __forceinline__ float dot16(float4 a0, float4 a1, float4 a2, float4 a3,
                                       float4 v0, float4 v1, float4 v2, float4 v3){
  float d = a0.x*v0.x + a0.y*v0.y + a0.z*v0.z + a0.w*v0.w;
  d += a1.x*v1.x + a1.y*v1.y + a1.z*v1.z + a1.w*v1.w;
  d += a2.x*v2.x + a2.y*v2.y + a2.z*v2.z + a2.w*v2.w;
  d += a3.x*v3.x + a3.y*v3.y + a3.z*v3.z + a3.w*v3.w;
  return d;
}

// ---------------- utility kernels ----------------

// both weight transposes in one launch. grid (32,32,2)
__global__ __launch_bounds__(256) void transpose2(
    const float* __restrict__ Wk, const float* __restrict__ Wk2,
    float* __restrict__ WkT, float* __restrict__ Wk2T){
  __shared__ float tile[32][33];
  const float* in  = blockIdx.z ? Wk2  : Wk;
  float*       outp= blockIdx.z ? Wk2T : WkT;
  int tx = threadIdx.x & 31, ty = threadIdx.x >> 5;
  int c0 = blockIdx.x * 32, r0 = blockIdx.y * 32;
#pragma unroll
  for (int k = 0; k < 4; ++k)
    tile[ty + 8*k][tx] = in[(size_t)(r0 + ty + 8*k) * Hn + c0 + tx];
  __syncthreads();
#pragma unroll
  for (int k = 0; k < 4; ++k)
    outp[(size_t)(c0 + ty + 8*k) * Hn + r0 + tx] = tile[tx][ty + 8*k];
}

// copy nums -> un  and  pq -> xs[:,0,:]. grid (Nn+1, Bn)
__global__ __launch_bounds__(256) void prep(
    const float4* __restrict__ nums, const float4* __restrict__ pq,
    float4* __restrict__ un, float4* __restrict__ xs){
  int n = blockIdx.x, b = blockIdx.y;
  if (n < Nn) un[((size_t)b*(Nn+Tn) + n)*256 + threadIdx.x] = nums[((size_t)b*Nn + n)*256 + threadIdx.x];
  else        xs[((size_t)b*Tn)*256 + threadIdx.x] = pq[(size_t)b*256 + threadIdx.x];
}

__global__ __launch_bounds__(256) void finalize_xs(const float4* __restrict__ xs, float4* __restrict__ uh, float4* __restrict__ un){
  int t = blockIdx.x, b = blockIdx.y;
  float4 v = xs[((size_t)b*Tn + t)*256 + threadIdx.x];
  uh[(((size_t)(Sn + t))*Bn + b)*256 + threadIdx.x] = v;
  un[((size_t)b*(Nn+Tn) + Nn + t)*256 + threadIdx.x] = v;
}

// ---------------- attention (gen loop), single-pass, all-f32 ----------------
// grid (16, B), block 512 = 8 waves x 4 rows. q built from the 16 split-K
// partials (saves the mv2 launch). Rows live in regs only 2 at a time
// (online pair-merge). One barrier; block reduce with per-wave rescale.
// FIRST also emits uh (folds the 64MB hidden copy).
template<int FIRST>
__global__ __launch_bounds__(512) void attend4(
    const float* __restrict__ hidden, const float* __restrict__ partk,
    float* __restrict__ ctxp, float* __restrict__ mlp, float* __restrict__ uh)
{
  const int b = blockIdx.y, p = blockIdx.x;
  const int tid = threadIdx.x, lane = tid & 63, w = tid >> 6;
  __shared__ float xq[1024];
  __shared__ float sM[8], sL[8];
  __shared__ float sacc[8*1024];

  // q[c] = sum over 16 k-partials (same order as mv2 did)
#pragma unroll
  for (int h0 = 0; h0 < 1024; h0 += 512){
    int c = h0 + tid;
    float s = 0.f;
#pragma unroll
    for (int i = 0; i < 16; ++i) s += partk[((size_t)(i*Bn + b))*1024 + c];
    xq[c] = s;
  }
  __syncthreads();
  float4 q0, q1, q2, q3;
  { const float4* xp = (const float4*)xq + lane*4; q0=xp[0]; q1=xp[1]; q2=xp[2]; q3=xp[3]; }

  const int s0 = p*32 + w*4;
  float m_run, l_run;
  float4 a0, a1, a2, a3;
  {
    // rows 0,1
    size_t r0 = ((size_t)(s0+0)*Bn + b)*Hn, r1 = ((size_t)(s0+1)*Bn + b)*Hn;
    const float4* rp0 = (const float4*)(hidden + r0) + lane*4;
    const float4* rp1 = (const float4*)(hidden + r1) + lane*4;
    float4 u0=rp0[0], u1=rp0[1], u2=rp0[2], u3=rp0[3];
    float4 v0=rp1[0], v1=rp1[1], v2=rp1[2], v3=rp1[3];
    if (FIRST){
      float4* w0p = (float4*)(uh + r0) + lane*4;
      float4* w1p = (float4*)(uh + r1) + lane*4;
      w0p[0]=u0; w0p[1]=u1; w0p[2]=u2; w0p[3]=u3;
      w1p[0]=v0; w1p[1]=v1; w1p[2]=v2; w1p[3]=v3;
    }
    float d0 = dot16(q0,q1,q2,q3, u0,u1,u2,u3);
    float d1 = dot16(q0,q1,q2,q3, v0,v1,v2,v3);
#pragma unroll
    for (int off = 32; off; off >>= 1){ d0 += __shfl_xor(d0, off); d1 += __shfl_xor(d1, off); }
    m_run = fmaxf(d0, d1);
    float w0 = __expf(d0 - m_run), w1 = __expf(d1 - m_run);
    l_run = w0 + w1;
    a0 = make_float4(w0*u0.x + w1*v0.x, w0*u0.y + w1*v0.y, w0*u0.z + w1*v0.z, w0*u0.w + w1*v0.w);
    a1 = make_float4(w0*u1.x + w1*v1.x, w0*u1.y + w1*v1.y, w0*u1.z + w1*v1.z, w0*u1.w + w1*v1.w);
    a2 = make_float4(w0*u2.x + w1*v2.x, w0*u2.y + w1*v2.y, w0*u2.z + w1*v2.z, w0*u2.w + w1*v2.w);
    a3 = make_float4(w0*u3.x + w1*v3.x, w0*u3.y + w1*v3.y, w0*u3.z + w1*v3.z, w0*u3.w + w1*v3.w);
  }
  {
    // rows 2,3 + online merge
    size_t r0 = ((size_t)(s0+2)*Bn + b)*Hn, r1 = ((size_t)(s0+3)*Bn + b)*Hn;
    const float4* rp0 = (const float4*)(hidden + r0) + lane*4;
    const float4* rp1 = (const float4*)(hidden + r1) + lane*4;
    float4 u0=rp0[0], u1=rp0[1], u2=rp0[2], u3=rp0[3];
    float4 v0=rp1[0], v1=rp1[1], v2=rp1[2], v3=rp1[3];
    if (FIRST){
      float4* w0p = (float4*)(uh + r0) + lane*4;
      float4* w1p = (float4*)(uh + r1) + lane*4;
      w0p[0]=u0; w0p[1]=u1; w0p[2]=u2; w0p[3]=u3;
      w1p[0]=v0; w1p[1]=v1; w1p[2]=v2; w1p[3]=v3;
    }
    float d0 = dot16(q0,q1,q2,q3, u0,u1,u2,u3);
    float d1 = dot16(q0,q1,q2,q3, v0,v1,v2,v3);
#pragma unroll
    for (int off = 32; off; off >>= 1){ d0 += __shfl_xor(d0, off); d1 += __shfl_xor(d1, off); }
    float mp = fmaxf(d0, d1);
    float mn = fmaxf(m_run, mp);
    float so = __expf(m_run - mn), sn = __expf(mp - mn);
    float w0 = __expf(d0 - mp) * sn, w1 = __expf(d1 - mp) * sn;
    l_run = l_run*so + w0 + w1;
    m_run = mn;
    a0.x = a0.x*so + w0*u0.x + w1*v0.x; a0.y = a0.y*so + w0*u0.y + w1*v0.y;
    a0.z = a0.z*so + w0*u0.z + w1*v0.z; a0.w = a0.w*so + w0*u0.w + w1*v0.w;
    a1.x = a1.x*so + w0*u1.x + w1*v1.x; a1.y = a1.y*so + w0*u1.y + w1*v1.y;
    a1.z = a1.z*so + w0*u1.z + w1*v1.z; a1.w = a1.w*so + w0*u1.w + w1*v1.w;
    a2.x = a2.x*so + w0*u2.x + w1*v2.x; a2.y = a2.y*so + w0*u2.y + w1*v2.y;
    a2.z = a2.z*so + w0*u2.z + w1*v2.z; a2.w = a2.w*so + w0*u2.w + w1*v2.w;
    a3.x = a3.x*so + w0*u3.x + w1*v3.x; a3.y = a3.y*so + w0*u3.y + w1*v3.y;
    a3.z = a3.z*so + w0*u3.z + w1*v3.z; a3.w = a3.w*so + w0*u3.w + w1*v3.w;
  }
  // swizzled store: slot' = slot ^ (lane&7) -> 8 consecutive lanes cover 32 banks
  {
    int sl0 = (lane*4 + 0) ^ (lane & 7);
    int sl1 = (lane*4 + 1) ^ (lane & 7);
    int sl2 = (lane*4 + 2) ^ (lane & 7);
    int sl3 = (lane*4 + 3) ^ (lane & 7);
    *(float4*)(sacc + w*1024 + sl0*4) = a0;
    *(float4*)(sacc + w*1024 + sl1*4) = a1;
    *(float4*)(sacc + w*1024 + sl2*4) = a2;
    *(float4*)(sacc + w*1024 + sl3*4) = a3;
  }
  if (lane == 0){ sM[w] = m_run; sL[w] = l_run; }
  __syncthreads();
  float M = sM[0];
#pragma unroll
  for (int i = 1; i < 8; ++i) M = fmaxf(M, sM[i]);
  float wex[8];
#pragma unroll
  for (int i = 0; i < 8; ++i) wex[i] = __expf(sM[i] - M);
#pragma unroll
  for (int h0 = 0; h0 < 1024; h0 += 512){
    int c = h0 + tid;
    int fo = (((c >> 2) ^ ((c >> 4) & 7)) << 2) + (c & 3);
    float s = 0.f;
#pragma unroll
    for (int i = 0; i < 8; ++i) s = fmaf(sacc[i*1024 + fo], wex[i], s);
    ctxp[((size_t)b*16 + p)*1024 + c] = s;
  }
  if (tid == 0){
    float L = 0.f;
#pragma unroll
    for (int i = 0; i < 8; ++i) L = fmaf(sL[i], wex[i], L);
    mlp[((size_t)b*16 + p)*2]     = M;
    mlp[((size_t)b*16 + p)*2 + 1] = L;
  }
}

// ---------------- split-K register-tiled matvec ----------------
__global__ __launch_bounds__(256) void mv1(
    const float* __restrict__ X, int xstride,
    const float* __restrict__ M, float* __restrict__ part,
    int nj, int ktiles)
{
  __shared__ float wt[64*128];
  __shared__ float xl[64*32];
  const int t  = threadIdx.x;
  const int j0 = blockIdx.x * 128;
  const int kb = blockIdx.y;
  const int r0 = blockIdx.z * 32;
  const int R  = gridDim.z * 32;
  const int tj = t & 31, tr = t >> 5;
  float acc[4][4] = {{0.f,0.f,0.f,0.f},{0.f,0.f,0.f,0.f},{0.f,0.f,0.f,0.f},{0.f,0.f,0.f,0.f}};

  for (int kt = 0; kt < ktiles; ++kt){
    const int k0 = (kb*ktiles + kt)*64;
    __syncthreads();
    {
      int j = t >> 1;
      int kqb = (t & 1) * 8;
      const float* Mrow = M + (size_t)(j0 + j)*1024 + k0;
#pragma unroll
      for (int c = 0; c < 8; ++c){
        float4 v = *(const float4*)(Mrow + (kqb + c)*4);
        int kk = (kqb + c)*4;
        wt[(kk+0)*128 + j] = v.x;
        wt[(kk+1)*128 + j] = v.y;
        wt[(kk+2)*128 + j] = v.z;
        wt[(kk+3)*128 + j] = v.w;
      }
      int r = t >> 3;
      int kq0 = t & 7;
#pragma unroll
      for (int c = 0; c < 2; ++c){
        int kk = (kq0 + c*8)*4;
        float4 v = *(const float4*)(X + (size_t)(r0 + r)*xstride + k0 + kk);
        xl[(kk+0)*32 + r] = v.x;
        xl[(kk+1)*32 + r] = v.y;
        xl[(kk+2)*32 + r] = v.z;
        xl[(kk+3)*32 + r] = v.w;
      }
    }
    __syncthreads();
#pragma unroll 4
    for (int k = 0; k < 64; ++k){
      float4 w4 = *(const float4*)(wt + k*128 + tj*4);
      float4 x4 = *(const float4*)(xl + k*32  + tr*4);
      acc[0][0] = fmaf(x4.x, w4.x, acc[0][0]);
      acc[0][1] = fmaf(x4.x, w4.y, acc[0][1]);
      acc[0][2] = fmaf(x4.x, w4.z, acc[0][2]);
      acc[0][3] = fmaf(x4.x, w4.w, acc[0][3]);
      acc[1][0] = fmaf(x4.y, w4.x, acc[1][0]);
      acc[1][1] = fmaf(x4.y, w4.y, acc[1][1]);
      acc[1][2] = fmaf(x4.y, w4.z, acc[1][2]);
      acc[1][3] = fmaf(x4.y, w4.w, acc[1][3]);
      acc[2][0] = fmaf(x4.z, w4.x, acc[2][0]);
      acc[2][1] = fmaf(x4.z, w4.y, acc[2][1]);
      acc[2][2] = fmaf(x4.z, w4.z, acc[2][2]);
      acc[2][3] = fmaf(x4.z, w4.w, acc[2][3]);
      acc[3][0] = fmaf(x4.w, w4.x, acc[3][0]);
      acc[3][1] = fmaf(x4.w, w4.y, acc[3][1]);
      acc[3][2] = fmaf(x4.w, w4.z, acc[3][2]);
      acc[3][3] = fmaf(x4.w, w4.w, acc[3][3]);
    }
  }
  const size_t base = ((size_t)kb*R + r0 + tr*4)*nj + j0 + tj*4;
#pragma unroll
  for (int i = 0; i < 4; ++i)
    *(float4*)(part + base + (size_t)i*nj) = make_float4(acc[i][0], acc[i][1], acc[i][2], acc[i][3]);
}

__global__ __launch_bounds__(256) void mv2(
    const float* __restrict__ part, int R, int njshift, int KB,
    const float* __restrict__ b1, const float* __restrict__ b2,
    float* __restrict__ out, int rpgshift, int opg)
{
  int idx = blockIdx.x*256 + threadIdx.x;
  int nj = 1 << njshift;
  int r = idx >> njshift, j = idx & (nj - 1);
  float s = 0.f;
  if (b1) s += b1[j];
  if (b2) s += b2[j];
  size_t stride = (size_t)R << njshift;
  for (int kb = 0; kb < KB; ++kb) s += part[(size_t)kb*stride + idx];
  int orow = ((r >> rpgshift) * opg) + (r & ((1 << rpgshift) - 1));
  out[((size_t)orow << njshift) + j] = s;
}

// ---------------- genstep: fused combine + Wv matvec (split-K) ----------------
// mv1 with the X-stage replaced by on-the-fly softmax-combine of ctxp/mlp.
// grid (8, 16), block 256. Writes split-K partials (mv2 adds bias -> xs[t]).
__global__ __launch_bounds__(256) void genstep(
    const float* __restrict__ ctxp, const float* __restrict__ mlp,
    const float* __restrict__ Wv, float* __restrict__ part)
{
  __shared__ float wt[64*128];
  __shared__ float xl[64*32];
  const int t  = threadIdx.x;
  const int j0 = blockIdx.x * 128;
  const int kb = blockIdx.y;
  const int k0 = kb*64;
  const int tj = t & 31, tr = t >> 5;

  {
    int j = t >> 1;
    int kqb = (t & 1) * 8;
    const float* Mrow = Wv + (size_t)(j0 + j)*1024 + k0;
#pragma unroll
    for (int c = 0; c < 8; ++c){
      float4 v = *(const float4*)(Mrow + (kqb + c)*4);
      int kk = (kqb + c)*4;
      wt[(kk+0)*128 + j] = v.x;
      wt[(kk+1)*128 + j] = v.y;
      wt[(kk+2)*128 + j] = v.z;
      wt[(kk+3)*128 + j] = v.w;
    }
  }
  {
    int b = t >> 3, kk = (t & 7)*8;
    float mm[16], ll[16], mx = -1e30f;
#pragma unroll
    for (int i = 0; i < 16; ++i){
      mm[i] = mlp[((size_t)b*16 + i)*2];
      ll[i] = mlp[((size_t)b*16 + i)*2 + 1];
      mx = fmaxf(mx, mm[i]);
    }
    float L = 0.f;
    float a8[8] = {0.f,0.f,0.f,0.f,0.f,0.f,0.f,0.f};
#pragma unroll
    for (int i = 0; i < 16; ++i){
      float we = __expf(mm[i] - mx);
      L = fmaf(ll[i], we, L);
      const float* cp = ctxp + ((size_t)b*16 + i)*1024 + k0 + kk;
      float4 u0 = *(const float4*)cp;
      float4 u1 = *(const float4*)(cp + 4);
      a8[0] = fmaf(we, u0.x, a8[0]); a8[1] = fmaf(we, u0.y, a8[1]);
      a8[2] = fmaf(we, u0.z, a8[2]); a8[3] = fmaf(we, u0.w, a8[3]);
      a8[4] = fmaf(we, u1.x, a8[4]); a8[5] = fmaf(we, u1.y, a8[5]);
      a8[6] = fmaf(we, u1.z, a8[6]); a8[7] = fmaf(we, u1.w, a8[7]);
    }
    float inv = 1.f / L;
#pragma unroll
    for (int q = 0; q < 8; ++q) xl[(kk + q)*32 + b] = a8[q]*inv;
  }
  __syncthreads();
  float acc[4][4] = {{0.f,0.f,0.f,0.f},{0.f,0.f,0.f,0.f},{0.f,0.f,0.f,0.f},{0.f,0.f,0.f,0.f}};
#pragma unroll 4
  for (int k = 0; k < 64; ++k){
    float4 w4 = *(const float4*)(wt + k*128 + tj*4);
    float4 x4 = *(const float4*)(xl + k*32  + tr*4);
    acc[0][0] = fmaf(x4.x, w4.x, acc[0][0]);
    acc[0][1] = fmaf(x4.x, w4.y, acc[0][1]);
    acc[0][2] = fmaf(x4.x, w4.z, acc[0][2]);
    acc[0][3] = fmaf(x4.x, w4.w, acc[0][3]);
    acc[1][0] = fmaf(x4.y, w4.x, acc[1][0]);
    acc[1][1] = fmaf(x4.y, w4.y, acc[1][1]);
    acc[1][2] = fmaf(x4.y, w4.z, acc[1][2]);
    acc[1][3] = fmaf(x4.y, w4.w, acc[1][3]);
    acc[2][0] = fmaf(x4.z, w4.x, acc[2][0]);
    acc[2][1] = fmaf(x4.z, w4.y, acc[2][1]);
    acc[2][2] = fmaf(x4.z, w4.z, acc[2][2]);
    acc[2][3] = fmaf(x4.z, w4.w, acc[2][3]);
    acc[3][0] = fmaf(x4.w, w4.x, acc[3][0]);
    acc[3][1] = fmaf(x4.w, w4.y, acc[3][1]);
    acc[3][2] = fmaf(x4.w, w4.z, acc[3][2]);
    acc[3][3] = fmaf(x4.w, w4.w, acc[3][3]);
  }
  const size_t base = ((size_t)kb*32 + tr*4)*1024 + j0 + tj*4;
#pragma unroll
  for (int i = 0; i < 4; ++i)
    *(float4*)(part + base + (size_t)i*1024) = make_float4(acc[i][0], acc[i][1], acc[i][2], acc[i][3]);
}

// ---------------- stage-2 kernels ----------------

__global__ __launch_bounds__(512) void scores2_kernel(
    const float* __restrict__ hidden, const float* __restrict__ xk2, float* __restrict__ sc)
{
  int b = blockIdx.y, p = blockIdx.x;
  int lane = threadIdx.x & 63, w = threadIdx.x >> 6;
  int t0 = (w & 3) * 2, rh = w >> 2;
  const float4* qa = (const float4*)(xk2 + ((size_t)b*Tn + t0  )*Hn) + lane*4;
  const float4* qb = (const float4*)(xk2 + ((size_t)b*Tn + t0+1)*Hn) + lane*4;
  float4 a0=qa[0], a1=qa[1], a2=qa[2], a3=qa[3];
  float4 c0=qb[0], c1=qb[1], c2=qb[2], c3=qb[3];
#pragma unroll 2
  for (int r = 0; r < 8; ++r){
    int s = p*16 + rh*8 + r;
    const float4* row = (const float4*)(hidden + ((size_t)s*Bn + b)*Hn) + lane*4;
    float4 v0=row[0], v1=row[1], v2=row[2], v3=row[3];
    float d0 = wsum(dot16(a0,a1,a2,a3, v0,v1,v2,v3));
    float d1 = wsum(dot16(c0,c1,c2,c3, v0,v1,v2,v3));
    if (lane == 0){
      sc[((size_t)b*Tn + t0  )*Sn + s] = d0;
      sc[((size_t)b*Tn + t0+1)*Sn + s] = d1;
    }
  }
}

__global__ __launch_bounds__(512) void ctx2f(
    const float* __restrict__ hidden, const float* __restrict__ scraw, float* __restrict__ ctx2)
{
  int b = blockIdx.y, hc = blockIdx.x, tid = threadIdx.x;
  __shared__ float al[Tn*Sn];
  for (int i = tid; i < Tn*Sn; i += 512) al[i] = scraw[(size_t)b*Tn*Sn + i];
  __syncthreads();
  {
    int r = tid >> 6, lane = tid & 63;
    float mx = -1e30f;
#pragma unroll
    for (int k = 0; k < 8; ++k) mx = fmaxf(mx, al[r*Sn + lane + k*64]);
#pragma unroll
    for (int off = 32; off; off >>= 1) mx = fmaxf(mx, __shfl_xor(mx, off));
    float e[8], s = 0.f;
#pragma unroll
    for (int k = 0; k < 8; ++k){ e[k] = __expf(al[r*Sn + lane + k*64] - mx); s += e[k]; }
#pragma unroll
    for (int off = 32; off; off >>= 1) s += __shfl_xor(s, off);
    float inv = 1.f / s;
#pragma unroll
    for (int k = 0; k < 8; ++k) al[r*Sn + lane + k*64] = e[k] * inv;
  }
  __syncthreads();
  int hloc = tid & 127, tg = tid >> 7;
  int h = hc*128 + hloc;
  int t0 = tg*2;
  float acc0 = 0.f, acc1 = 0.f;
#pragma unroll 4
  for (int s = 0; s < Sn; ++s){
    float v = hidden[((size_t)s*Bn + b)*Hn + h];
    acc0 = fmaf(al[t0*Sn + s],     v, acc0);
    acc1 = fmaf(al[(t0+1)*Sn + s], v, acc1);
  }
  ctx2[((size_t)b*Tn + t0  )*Hn + h] = acc0;
  ctx2[((size_t)b*Tn + t0+1)*Hn + h] = acc1;
}

// ---------------- LSTM: fused partial-reduce + pointwise ----------------
__global__ __launch_bounds__(256) void lstm_fused(
    const float* __restrict__ part, const float* __restrict__ b_ih,
    const float* __restrict__ b_hh, float* __restrict__ fq)
{
  int idx = blockIdx.x*256 + threadIdx.x;   // 32768
  int b = idx >> 10, h = idx & 1023;
  const size_t stride = (size_t)32*Gn;
  float gi = b_ih[h] + b_hh[h];
  float gg = b_ih[2048+h] + b_hh[2048+h];
  float go = b_ih[3072+h] + b_hh[3072+h];
  for (int kb = 0; kb < 16; ++kb){
    const float* pp = part + (size_t)kb*stride + (size_t)b*Gn;
    gi += pp[h]; gg += pp[2048+h]; go += pp[3072+h];
  }
  float si = 1.f/(1.f + __expf(-gi));
  float so = 1.f/(1.f + __expf(-go));
  float c  = si * tanhf(gg);
  fq[((size_t)b*(Tn+1) + Tn)*Hn + h] = so * tanhf(c);
}

// ---------------- host ----------------

extern "C" void kernel_launch(void* const* d_in, const int* in_sizes, int n_in,
                              void* d_out, int out_size, void* d_ws, size_t ws_size,
                              hipStream_t stream) {
  const float* hidden = (const float*)d_in[0];
  const float* nums   = (const float*)d_in[1];
  const float* pq     = (const float*)d_in[2];
  const float* Wk     = (const float*)d_in[3];
  const float* Wv     = (const float*)d_in[5];
  const float* bv     = (const float*)d_in[6];
  const float* Wk2    = (const float*)d_in[7];
  const float* Wv2    = (const float*)d_in[9];
  const float* bv2    = (const float*)d_in[10];
  const float* W_ih   = (const float*)d_in[11];
  const float* b_ih   = (const float*)d_in[13];
  const float* b_hh   = (const float*)d_in[14];

  float* out = (float*)d_out;
  float* fq  = out;                                   // (B, T+1, H)
  float* uh  = out + (size_t)Bn*(Tn+1)*Hn;            // (S+T, B, H)
  float* un  = uh + (size_t)(Sn+Tn)*Bn*Hn;            // (B, N+T, H)

  // ws layout (floats); high-water 4,588,544 floats = 18.35 MB (< proven 21.25 MB)
  float* ws    = (float*)d_ws;
  float* xs    = ws;                 // 262144
  float* ctxp  = ws + 262144;        // 524288 (B*16*H)
  float* mlp   = ws + 786432;        // 1024
  float* xk2   = ws + 787456;        // 262144
  float* sc2   = ws + 1049600;       // 131072
  float* ctx2v = ws + 1180672;       // 262144
  float* partX = ws + 1442816;       // 524288 (16*32*1024)
  float* partK = ws + 1967104;       // 524288 (16*32*1024)
  float* WkT   = ws + 2491392;       // 1048576
  float* Wk2T  = ws + 3539968;       // 1048576
  float* partS = partX;              // stage-2 partials 4*256*1024 = 1048576 (spans partX+partK, both dead)
  float* partL = WkT;                // LSTM partials 16*32*4096 = 2097152 (spans WkT+Wk2T, both dead;
                                     // rewritten every call -> replay-safe)

  transpose2<<<dim3(32,32,2), 256, 0, stream>>>(Wk, Wk2, WkT, Wk2T);
  prep<<<dim3(Nn+1, Bn), 256, 0, stream>>>((const float4*)nums, (const float4*)pq, (float4*)un, (float4*)xs);

  // q0 partials = Wk^T problem_q (attend sums the 16 partials itself)
  mv1<<<dim3(8,16,1), 256, 0, stream>>>(pq, Hn, WkT, partK, Hn, 1);

  for (int t = 1; t < Tn; ++t){
    if (t == 1) attend4<1><<<dim3(16,Bn), 512, 0, stream>>>(hidden, partK, ctxp, mlp, uh);
    else        attend4<0><<<dim3(16,Bn), 512, 0, stream>>>(hidden, partK, ctxp, mlp, uh);
    genstep<<<dim3(8,16), 256, 0, stream>>>(ctxp, mlp, Wv, partX);
    mv2<<<128, 256, 0, stream>>>(partX, 32, 10, 16, bv, nullptr, xs + (size_t)t*Hn, 0, Tn);
    if (t < Tn-1)
      mv1<<<dim3(8,16,1), 256, 0, stream>>>(xs + (size_t)t*Hn, Tn*Hn, WkT, partK, Hn, 1);
  }

  // stage 2
  mv1<<<dim3(8,4,8), 256, 0, stream>>>(xs, Hn, Wk2T, partS, Hn, 4);
  mv2<<<1024, 256, 0, stream>>>(partS, 256, 10, 4, nullptr, nullptr, xk2, 0, 1);
  scores2_kernel<<<dim3(32, Bn), 512, 0, stream>>>(hidden, xk2, sc2);
  ctx2f<<<dim3(8, Bn), 512, 0, stream>>>(hidden, sc2, ctx2v);
  mv1<<<dim3(8,4,8), 256, 0, stream>>>(ctx2v, Hn, Wv2, partS, Hn, 4);
  mv2<<<1024, 256, 0, stream>>>(partS, 256, 10, 4, bv2, nullptr, fq, 3, Tn+1);

  // LSTM step 1 (partials overlay WkT/Wk2T -- dead by now)
  mv1<<<dim3(32,16,1), 256, 0, stream>>>(fq, (Tn+1)*Hn, W_ih, partL, Gn, 1);
  lstm_fused<<<128, 256, 0, stream>>>(partL, b_ih, b_hh, fq);

  finalize_xs<<<dim3(Tn, Bn), 256, 0, stream>>>((const float4*)xs, (float4*)uh, (float4*)un);
}